// Round 1
// baseline (179.368 us; speedup 1.0000x reference)
//
#include <hip/hip_runtime.h>
#include <math.h>

#define NB 4
#define LL 4096
#define DD 1024
#define MM 256

typedef short s16x8 __attribute__((ext_vector_type(8)));
typedef short s16x4 __attribute__((ext_vector_type(4)));
typedef float fx4 __attribute__((ext_vector_type(4)));

__device__ __forceinline__ float b2f(short s) {
  union { unsigned u; float f; } v;
  v.u = ((unsigned)(unsigned short)s) << 16;
  return v.f;
}
__device__ __forceinline__ short f2b(float f) {
  union { float f; unsigned u; } v;
  v.f = f;
  unsigned r = (v.u + 0x7fffu + ((v.u >> 16) & 1u)) >> 16;
  return (short)(unsigned short)r;
}
// all MFMA LDS tiles have 64-element (128B) rows; XOR swizzle on 8-elem granule
__device__ __forceinline__ int swz(int row, int col) {
  return row * 64 + (col ^ ((row & 7) << 3));
}

typedef __attribute__((address_space(1))) const void* gas1_t;
typedef __attribute__((address_space(3))) void* las3_t;
#define GLL16(g, l) __builtin_amdgcn_global_load_lds((gas1_t)(const void*)(g), (las3_t)(void*)(l), 16, 0, 0)

// ---------------- cast fp32 -> bf16 (vectorized) ----------------
__global__ __launch_bounds__(256) void k_cast(const float* __restrict__ in, short* __restrict__ out, int n4) {
  int i = blockIdx.x * 256 + threadIdx.x;
  if (i >= n4) return;
  float4 v = ((const float4*)in)[i];
  s16x4 s;
  s[0] = f2b(v.x); s[1] = f2b(v.y); s[2] = f2b(v.z); s[3] = f2b(v.w);
  ((s16x4*)out)[i] = s;
}

// ---------------- V (B,L,D) fp32 -> VT (B,D,L) bf16 ----------------
__global__ __launch_bounds__(256) void k_vt(const float* __restrict__ V, short* __restrict__ VT) {
  __shared__ float t[64][65];
  int b = blockIdx.z, l0 = blockIdx.x * 64, d0 = blockIdx.y * 64;
  int tid = threadIdx.x;
  int r = tid >> 2, q = tid & 3;
  const float* src = V + ((size_t)b * LL + l0 + r) * DD + d0 + q * 16;
  #pragma unroll
  for (int i = 0; i < 16; i += 4) {
    float4 v = *(const float4*)(src + i);
    t[r][q * 16 + i + 0] = v.x;
    t[r][q * 16 + i + 1] = v.y;
    t[r][q * 16 + i + 2] = v.z;
    t[r][q * 16 + i + 3] = v.w;
  }
  __syncthreads();
  int a = tid & 31, dg = tid >> 5;
  #pragma unroll
  for (int j = 0; j < 8; ++j) {
    int d = dg * 8 + j;
    unsigned lo = (unsigned short)f2b(t[2 * a][d]);
    unsigned hi = (unsigned short)f2b(t[2 * a + 1][d]);
    *(unsigned*)(VT + ((size_t)b * DD + d0 + d) * LL + l0 + 2 * a) = lo | (hi << 16);
  }
}

// ---------------- rf GEMM: C(64,256) = X(64,1024) x Pb(256,1024)^T, exp epilogue ----------------
// mode 0: out = rf_q (B,L,M) bf16, includes 1/sqrt(M)
// mode 1: out = rf_kT (B,M,L) bf16 (transposed store via LDS bounce)
__global__ __launch_bounds__(256) void k_rf(const float* __restrict__ X, const short* __restrict__ Pb,
                                            short* __restrict__ out, int mode) {
  __shared__ short Al[64 * 64];
  __shared__ short Bl[256 * 64];  // Pb tile; reused as transpose bounce in mode 1
  int b = blockIdx.y, l0 = blockIdx.x * 64;
  int tid = threadIdx.x, lane = tid & 63, w = tid >> 6;
  fx4 acc[4][4] = {};
  for (int d0 = 0; d0 < DD; d0 += 64) {
    // stage A: fp32 load (fully coalesced) -> bf16 -> swizzled LDS
    #pragma unroll
    for (int j = 0; j < 4; ++j) {
      int f4 = tid + j * 256, row = f4 >> 4, c4 = f4 & 15;
      float4 v = *(const float4*)(X + ((size_t)b * LL + l0 + row) * DD + d0 + c4 * 4);
      s16x4 s;
      s[0] = f2b(v.x); s[1] = f2b(v.y); s[2] = f2b(v.z); s[3] = f2b(v.w);
      *(s16x4*)&Al[row * 64 + ((c4 * 4) ^ ((row & 7) << 3))] = s;
    }
    // stage B: bf16 Pb via global_load_lds, source pre-swizzled (linear LDS dest)
    #pragma unroll
    for (int j = 0; j < 8; ++j) {
      int fl = tid + j * 256, row = fl >> 3, c8 = fl & 7;
      GLL16(Pb + row * DD + d0 + (c8 ^ (row & 7)) * 8, &Bl[fl * 8]);
    }
    __syncthreads();
    #pragma unroll
    for (int ks = 0; ks < 2; ++ks) {
      int kb = ks * 32 + (lane >> 4) * 8;
      s16x8 af[4], bf[4];
      #pragma unroll
      for (int mi = 0; mi < 4; ++mi) af[mi] = *(const s16x8*)&Al[swz(mi * 16 + (lane & 15), kb)];
      #pragma unroll
      for (int ni = 0; ni < 4; ++ni) bf[ni] = *(const s16x8*)&Bl[swz(w * 64 + ni * 16 + (lane & 15), kb)];
      #pragma unroll
      for (int mi = 0; mi < 4; ++mi)
        #pragma unroll
        for (int ni = 0; ni < 4; ++ni)
          acc[mi][ni] = __builtin_amdgcn_mfma_f32_16x16x32_bf16(af[mi], bf[ni], acc[mi][ni], 0, 0, 0);
    }
    __syncthreads();
  }
  if (mode == 0) {
    #pragma unroll
    for (int mi = 0; mi < 4; ++mi)
      #pragma unroll
      for (int ni = 0; ni < 4; ++ni) {
        int r0 = mi * 16 + ((lane >> 4) << 2);
        int c = w * 64 + ni * 16 + (lane & 15);
        #pragma unroll
        for (int u = 0; u < 4; ++u)
          out[((size_t)b * LL + l0 + r0 + u) * MM + c] = f2b(expf(acc[mi][ni][u] * 0.03125f) * 0.0625f);
      }
  } else {
    // write C^T into Bl (swizzled by col-row), then coalesced store to (B,M,L)
    #pragma unroll
    for (int mi = 0; mi < 4; ++mi)
      #pragma unroll
      for (int ni = 0; ni < 4; ++ni) {
        int r0 = mi * 16 + ((lane >> 4) << 2);
        int c = w * 64 + ni * 16 + (lane & 15);
        s16x4 s;
        #pragma unroll
        for (int u = 0; u < 4; ++u) s[u] = f2b(expf(acc[mi][ni][u] * 0.03125f));
        *(s16x4*)&Bl[c * 64 + (r0 ^ ((c & 7) << 3))] = s;
      }
    __syncthreads();
    for (int j = 0; j < 32; ++j) {
      int m = j * 8 + (tid >> 5), a = tid & 31, rr = a * 2;
      unsigned uv = *(const unsigned*)&Bl[m * 64 + (rr ^ ((m & 7) << 3))];
      *(unsigned*)(out + ((size_t)b * MM + m) * LL + l0 + rr) = uv;
    }
  }
}

// ---------------- Z[b][m] = sum_l rf_kT[b][m][l] ----------------
__global__ __launch_bounds__(256) void k_z(const short* __restrict__ rfkT, float* __restrict__ Z) {
  int g = blockIdx.x * 4 + (threadIdx.x >> 6);
  int lane = threadIdx.x & 63;
  int b = g >> 8, m = g & 255;
  const s16x8* p = (const s16x8*)(rfkT + ((size_t)b * MM + m) * LL);
  float s = 0.f;
  #pragma unroll
  for (int j = 0; j < 8; ++j) {
    s16x8 v = p[lane + j * 64];
    #pragma unroll
    for (int i = 0; i < 8; ++i) s += b2f(v[i]);
  }
  for (int off = 32; off; off >>= 1) s += __shfl_down(s, off);
  if (lane == 0) Z[b * MM + m] = s;
}

// ---------------- KVT[b][d][m] += sum_l VT[d][l]*rf_kT[m][l], split-K atomics ----------------
__global__ __launch_bounds__(512) void k_kv(const short* __restrict__ VT, const short* __restrict__ rfkT,
                                            float* __restrict__ KVTf) {
  __shared__ short Avl[128 * 64];
  __shared__ short Bkl[256 * 64];
  int d0 = blockIdx.x * 128, kc = blockIdx.y, b = blockIdx.z;
  int tid = threadIdx.x, lane = tid & 63, w = tid >> 6;
  int wr = w >> 2, wc = w & 3;
  fx4 acc[4][4] = {};
  const short* Abase = VT + ((size_t)b * DD + d0) * LL + kc * 512;
  const short* Bbase = rfkT + ((size_t)b * MM) * LL + kc * 512;
  for (int it = 0; it < 8; ++it) {
    int lc = it * 64;
    #pragma unroll
    for (int j = 0; j < 2; ++j) {
      int fl = tid + j * 512, row = fl >> 3, c8 = fl & 7;
      GLL16(Abase + (size_t)row * LL + lc + (c8 ^ (row & 7)) * 8, &Avl[fl * 8]);
    }
    #pragma unroll
    for (int j = 0; j < 4; ++j) {
      int fl = tid + j * 512, row = fl >> 3, c8 = fl & 7;
      GLL16(Bbase + (size_t)row * LL + lc + (c8 ^ (row & 7)) * 8, &Bkl[fl * 8]);
    }
    __syncthreads();
    #pragma unroll
    for (int ks = 0; ks < 2; ++ks) {
      int kb = ks * 32 + (lane >> 4) * 8;
      s16x8 af[4], bf[4];
      #pragma unroll
      for (int mi = 0; mi < 4; ++mi) af[mi] = *(const s16x8*)&Avl[swz(wr * 64 + mi * 16 + (lane & 15), kb)];
      #pragma unroll
      for (int ni = 0; ni < 4; ++ni) bf[ni] = *(const s16x8*)&Bkl[swz(wc * 64 + ni * 16 + (lane & 15), kb)];
      #pragma unroll
      for (int mi = 0; mi < 4; ++mi)
        #pragma unroll
        for (int ni = 0; ni < 4; ++ni)
          acc[mi][ni] = __builtin_amdgcn_mfma_f32_16x16x32_bf16(af[mi], bf[ni], acc[mi][ni], 0, 0, 0);
    }
    __syncthreads();
  }
  #pragma unroll
  for (int mi = 0; mi < 4; ++mi)
    #pragma unroll
    for (int ni = 0; ni < 4; ++ni)
      #pragma unroll
      for (int u = 0; u < 4; ++u) {
        int dd2 = d0 + wr * 64 + mi * 16 + ((lane >> 4) << 2) + u;
        int mm2 = wc * 64 + ni * 16 + (lane & 15);
        atomicAdd(&KVTf[((size_t)b * DD + dd2) * MM + mm2], acc[mi][ni][u]);
      }
}

// ---------------- out = (rf_q x KVT^T) / (rf_q . Z + eps) ----------------
__global__ __launch_bounds__(512) void k_out(const short* __restrict__ rfq, const short* __restrict__ KVTb,
                                             const float* __restrict__ Z, float* __restrict__ out) {
  __shared__ short Aql[128 * 64];
  __shared__ short Bkv[128 * 64];
  __shared__ float zl[256];
  __shared__ float np[512];
  __shared__ float nf[128];
  int l0 = blockIdx.x * 128, d0 = blockIdx.y * 128, b = blockIdx.z;
  int tid = threadIdx.x, lane = tid & 63, w = tid >> 6;
  int wr = w >> 1, wc = w & 1;
  if (tid < 256) zl[tid] = Z[b * MM + tid];
  fx4 acc[2][4] = {};
  float na = 0.f;
  int nrow = tid & 127, nsub = tid >> 7;
  for (int it = 0; it < 4; ++it) {
    int m0 = it * 64;
    #pragma unroll
    for (int j = 0; j < 2; ++j) {
      int fl = tid + j * 512, row = fl >> 3, c8 = fl & 7;
      GLL16(rfq + ((size_t)b * LL + l0 + row) * MM + m0 + (c8 ^ (row & 7)) * 8, &Aql[fl * 8]);
    }
    #pragma unroll
    for (int j = 0; j < 2; ++j) {
      int fl = tid + j * 512, row = fl >> 3, c8 = fl & 7;
      GLL16(KVTb + ((size_t)b * DD + d0 + row) * MM + m0 + (c8 ^ (row & 7)) * 8, &Bkv[fl * 8]);
    }
    __syncthreads();
    // normalizer partial: 4 threads per row, 16 k each
    #pragma unroll
    for (int kk = 0; kk < 16; ++kk) {
      int k = nsub * 16 + kk;
      na += b2f(Aql[nrow * 64 + (k ^ ((nrow & 7) << 3))]) * zl[m0 + k];
    }
    #pragma unroll
    for (int ks = 0; ks < 2; ++ks) {
      int kb = ks * 32 + (lane >> 4) * 8;
      s16x8 af[2], bf[4];
      #pragma unroll
      for (int mi = 0; mi < 2; ++mi) af[mi] = *(const s16x8*)&Aql[swz(wr * 32 + mi * 16 + (lane & 15), kb)];
      #pragma unroll
      for (int ni = 0; ni < 4; ++ni) bf[ni] = *(const s16x8*)&Bkv[swz(wc * 64 + ni * 16 + (lane & 15), kb)];
      #pragma unroll
      for (int mi = 0; mi < 2; ++mi)
        #pragma unroll
        for (int ni = 0; ni < 4; ++ni)
          acc[mi][ni] = __builtin_amdgcn_mfma_f32_16x16x32_bf16(af[mi], bf[ni], acc[mi][ni], 0, 0, 0);
    }
    __syncthreads();
  }
  np[tid] = na;
  __syncthreads();
  if (tid < 128) nf[tid] = np[tid] + np[tid + 128] + np[tid + 256] + np[tid + 384] + 1e-6f;
  __syncthreads();
  #pragma unroll
  for (int mi = 0; mi < 2; ++mi)
    #pragma unroll
    for (int ni = 0; ni < 4; ++ni) {
      int r0 = wr * 32 + mi * 16 + ((lane >> 4) << 2);
      int c = d0 + wc * 64 + ni * 16 + (lane & 15);
      #pragma unroll
      for (int u = 0; u < 4; ++u)
        out[((size_t)b * LL + l0 + r0 + u) * DD + c] = acc[mi][ni][u] / nf[r0 + u];
    }
}

extern "C" void kernel_launch(void* const* d_in, const int* in_sizes, int n_in,
                              void* d_out, int out_size, void* d_ws, size_t ws_size,
                              hipStream_t stream) {
  const float* Q = (const float*)d_in[0];
  const float* K = (const float*)d_in[1];
  const float* V = (const float*)d_in[2];
  const float* P = (const float*)d_in[3];
  float* out = (float*)d_out;
  char* ws = (char*)d_ws;

  short* Pb   = (short*)(ws + 0);          // 256*1024*2      = 512 KB
  short* VT   = (short*)(ws + 524288);     // 4*1024*4096*2   = 32 MB
  short* rfq  = (short*)(ws + 34078720);   // 4*4096*256*2    = 8 MB
  short* rfkT = (short*)(ws + 42467328);   // 4*256*4096*2    = 8 MB
  float* Zz   = (float*)(ws + 50855936);   // 4*256*4         = 4 KB
  float* KVTf = (float*)(ws + 50860032);   // 4*1024*256*4    = 4 MB
  short* KVTb = (short*)(ws + 55054336);   // 4*1024*256*2    = 2 MB

  k_cast<<<256, 256, 0, stream>>>(P, Pb, 65536);
  k_vt<<<dim3(64, 16, NB), 256, 0, stream>>>(V, VT);
  k_rf<<<dim3(64, NB), 256, 0, stream>>>(Q, Pb, rfq, 0);
  k_rf<<<dim3(64, NB), 256, 0, stream>>>(K, Pb, rfkT, 1);
  k_z<<<256, 256, 0, stream>>>(rfkT, Zz);
  (void)hipMemsetAsync(KVTf, 0, (size_t)NB * DD * MM * sizeof(float), stream);
  k_kv<<<dim3(8, 8, NB), 512, 0, stream>>>(VT, rfkT, KVTf);
  k_cast<<<1024, 256, 0, stream>>>(KVTf, KVTb, 262144);
  k_out<<<dim3(32, 8, NB), 512, 0, stream>>>(rfq, KVTb, Zz, out);
}